// Round 3
// baseline (7496.339 us; speedup 1.0000x reference)
//
#include <hip/hip_runtime.h>
#include <hip/hip_bf16.h>
#include <math.h>

typedef __hip_bfloat16 bf16;

// Problem constants: B=4, S=2048, H=1024, K=64, NH=16, d=64, L=2, FF=2730, EPS=1e-6
// Dtype (verified round 3 theory): ALL inputs fp32, output fp32 (reference dtypes).
// Comparison is done at bf16 tolerance (threshold = 2% of ref absmax).

__device__ __forceinline__ float ldf(const float* p, long i){ return p[i]; }
__device__ __forceinline__ float ldf(const bf16*  p, long i){ return __bfloat162float(p[i]); }
__device__ __forceinline__ void  stf(float* p, long i, float v){ p[i] = v; }
__device__ __forceinline__ void  stf(bf16*  p, long i, float v){ p[i] = __float2bfloat16(v); }

// ---------------- stable descending argsort of chunk_weights (K=64) -------------
__global__ void sort_chunks_k(const float* __restrict__ w, int* __restrict__ sidx){
    int b = blockIdx.x, t = threadIdx.x;           // 64 threads
    __shared__ float ws_[64];
    ws_[t] = w[b*64 + t];
    __syncthreads();
    float mine = ws_[t];
    int rank = 0;
    for (int j = 0; j < 64; j++){
        float wj = ws_[j];
        rank += (wj > mine) || (wj == mine && j < t);   // stable: ties by lower index first
    }
    sidx[b*64 + rank] = t;
}

__global__ void gather_k(const float* __restrict__ src, const int* __restrict__ sidx,
                         float* __restrict__ dst){
    int row = blockIdx.x; int b = row >> 6, r = row & 63;
    int sr = sidx[b*64 + r];
    const float* s = src + ((long)(b*64 + sr))*1024;
    float* d = dst + (long)row*1024;
    for (int i = threadIdx.x; i < 1024; i += 256) d[i] = s[i];
}

__global__ void scatter_k(const float* __restrict__ x, const int* __restrict__ sidx,
                          float* __restrict__ proc){
    int row = blockIdx.x; int b = row >> 6, r = row & 63;
    int dr = sidx[b*64 + r];
    const float* s = x + (long)row*1024;
    float* d = proc + ((long)(b*64 + dr))*1024;
    for (int i = threadIdx.x; i < 1024; i += 256) d[i] = s[i];
}

// ---------------- RMSNorm (row length fixed 1024) --------------------------------
__global__ __launch_bounds__(256) void rms_k(const float* __restrict__ x,
                                             const float* __restrict__ w,
                                             float* __restrict__ o){
    long row = blockIdx.x;
    const float* xr = x + row*1024;
    float v[4]; float ss = 0.f;
    #pragma unroll
    for (int j = 0; j < 4; j++){ v[j] = xr[threadIdx.x + j*256]; ss += v[j]*v[j]; }
    #pragma unroll
    for (int off = 32; off; off >>= 1) ss += __shfl_down(ss, off, 64);
    __shared__ float red[4];
    __shared__ float scale_s;
    int wave = threadIdx.x >> 6, lane = threadIdx.x & 63;
    if (lane == 0) red[wave] = ss;
    __syncthreads();
    if (threadIdx.x == 0){
        float t = red[0] + red[1] + red[2] + red[3];
        scale_s = rsqrtf(t * (1.0f/1024.f) + 1e-6f);
    }
    __syncthreads();
    float sc = scale_s;
    #pragma unroll
    for (int j = 0; j < 4; j++){
        int i = threadIdx.x + j*256;
        o[row*1024 + i] = v[j] * sc * w[i];
    }
}

// ---------------- Generic tiled GEMM: C = A @ W^T (+bias)(+Res) -------------------
// A: M x K (TA), W: N x K (fp32 row-major), C: M x N (TC), Res: M x N (TR, optional)
template<typename TA, typename TC, typename TR>
__global__ __launch_bounds__(256) void gemm_k(
    const TA* __restrict__ A, const float* __restrict__ W,
    const float* __restrict__ bias, const TR* __restrict__ Res,
    TC* __restrict__ C, int M, int N, int Kd)
{
    __shared__ float As[16][65];
    __shared__ float Ws[16][65];
    const int bm = blockIdx.y*64, bn = blockIdx.x*64;
    const int tid = threadIdx.x;
    const int tx = tid & 15, ty = tid >> 4;
    float acc[4][4] = {};
    for (int k0 = 0; k0 < Kd; k0 += 16){
        for (int e = tid; e < 1024; e += 256){
            int m = e >> 4, kk = e & 15;
            int gk = k0 + kk;
            int gm = bm + m;
            int gn = bn + m;
            As[kk][m] = (gm < M && gk < Kd) ? ldf(A, (long)gm*Kd + gk) : 0.f;
            Ws[kk][m] = (gn < N && gk < Kd) ? W[(long)gn*Kd + gk] : 0.f;
        }
        __syncthreads();
        #pragma unroll
        for (int kk = 0; kk < 16; kk++){
            float a[4], b[4];
            #pragma unroll
            for (int i = 0; i < 4; i++) a[i] = As[kk][ty*4+i];
            #pragma unroll
            for (int j = 0; j < 4; j++) b[j] = Ws[kk][tx*4+j];
            #pragma unroll
            for (int i = 0; i < 4; i++)
                #pragma unroll
                for (int j = 0; j < 4; j++)
                    acc[i][j] = fmaf(a[i], b[j], acc[i][j]);
        }
        __syncthreads();
    }
    #pragma unroll
    for (int i = 0; i < 4; i++){
        int m = bm + ty*4 + i;
        if (m >= M) continue;
        #pragma unroll
        for (int j = 0; j < 4; j++){
            int n = bn + tx*4 + j;
            if (n >= N) continue;
            float v = acc[i][j];
            if (bias) v += bias[n];
            if (Res)  v += ldf(Res, (long)m*N + n);
            stf(C, (long)m*N + n, v);
        }
    }
}

// ---------------- Gated FFN GEMM: C = silu(A@W1^T) * (A@W3^T) --------------------
template<typename TC>
__global__ __launch_bounds__(256) void gemm_gated_k(
    const float* __restrict__ A, const float* __restrict__ W1,
    const float* __restrict__ W3, TC* __restrict__ C,
    int M, int N, int Kd)
{
    __shared__ float As [16][65];
    __shared__ float W1s[16][65];
    __shared__ float W3s[16][65];
    const int bm = blockIdx.y*64, bn = blockIdx.x*64;
    const int tid = threadIdx.x;
    const int tx = tid & 15, ty = tid >> 4;
    float acc1[4][4] = {};
    float acc3[4][4] = {};
    for (int k0 = 0; k0 < Kd; k0 += 16){
        for (int e = tid; e < 1024; e += 256){
            int m = e >> 4, kk = e & 15;
            int gk = k0 + kk;
            int gm = bm + m;
            int gn = bn + m;
            As [kk][m] = (gm < M && gk < Kd) ? A[(long)gm*Kd + gk] : 0.f;
            W1s[kk][m] = (gn < N && gk < Kd) ? W1[(long)gn*Kd + gk] : 0.f;
            W3s[kk][m] = (gn < N && gk < Kd) ? W3[(long)gn*Kd + gk] : 0.f;
        }
        __syncthreads();
        #pragma unroll
        for (int kk = 0; kk < 16; kk++){
            float a[4], b1[4], b3[4];
            #pragma unroll
            for (int i = 0; i < 4; i++) a[i]  = As[kk][ty*4+i];
            #pragma unroll
            for (int j = 0; j < 4; j++){ b1[j] = W1s[kk][tx*4+j]; b3[j] = W3s[kk][tx*4+j]; }
            #pragma unroll
            for (int i = 0; i < 4; i++)
                #pragma unroll
                for (int j = 0; j < 4; j++){
                    acc1[i][j] = fmaf(a[i], b1[j], acc1[i][j]);
                    acc3[i][j] = fmaf(a[i], b3[j], acc3[i][j]);
                }
        }
        __syncthreads();
    }
    #pragma unroll
    for (int i = 0; i < 4; i++){
        int m = bm + ty*4 + i;
        if (m >= M) continue;
        #pragma unroll
        for (int j = 0; j < 4; j++){
            int n = bn + tx*4 + j;
            if (n >= N) continue;
            float x1 = acc1[i][j];
            float g  = x1 / (1.0f + expf(-x1));     // silu
            stf(C, (long)m*N + n, g * acc3[i][j]);
        }
    }
}

// ---------------- Cascade causal self-attention (K=64, d=64, per (b,h)) ----------
__global__ __launch_bounds__(64) void casc_attn_k(const float* __restrict__ qkv,
                                                  float* __restrict__ o){
    int b = blockIdx.x >> 4, h = blockIdx.x & 15;
    __shared__ float Ks[64][64], Vs[64][64], Sc[64][64];
    int t = threadIdx.x;
    const float* base = qkv + ((long)(b*64 + t))*3072 + h*64;
    float qr[64];
    #pragma unroll
    for (int i = 0; i < 64; i++){
        qr[i]    = base[i];
        Ks[t][i] = base[1024 + i];
        Vs[t][i] = base[2048 + i];
    }
    __syncthreads();
    float m = -1e30f;
    for (int j = 0; j <= t; j++){               // causal: key j <= query t
        float dot = 0.f;
        #pragma unroll
        for (int i = 0; i < 64; i++) dot = fmaf(qr[i], Ks[j][i], dot);
        dot *= 0.125f;
        Sc[t][j] = dot;
        m = fmaxf(m, dot);
    }
    float l = 0.f;
    for (int j = 0; j <= t; j++){ float e = expf(Sc[t][j] - m); Sc[t][j] = e; l += e; }
    float inv = 1.f / l;
    float* op = o + ((long)(b*64 + t))*1024 + h*64;
    for (int i = 0; i < 64; i++){
        float acc = 0.f;
        for (int j = 0; j <= t; j++) acc = fmaf(Sc[t][j], Vs[j][i], acc);
        op[i] = acc * inv;
    }
}

// ---------------- Decoder cross-attention: 64-token tile x 64 chunks -------------
__global__ __launch_bounds__(256) void dec_attn_k(const float* __restrict__ q,
    const float* __restrict__ kk, const float* __restrict__ vv, float* __restrict__ o){
    int s0 = blockIdx.x*64, h = blockIdx.y, b = blockIdx.z;
    __shared__ float Ks[64][64], Vs[64][64], Sc[64][65];
    int tid = threadIdx.x;
    for (int e = tid; e < 4096; e += 256){
        int c = e >> 6, i = e & 63;
        Ks[c][i] = kk[((long)(b*64 + c))*1024 + h*64 + i];
        Vs[c][i] = vv[((long)(b*64 + c))*1024 + h*64 + i];
    }
    __syncthreads();
    int r = tid >> 2, seg = tid & 3;
    int s = s0 + r;
    float qr[64];
    const float* qp = q + ((long)(b*2048 + s))*1024 + h*64;
    #pragma unroll
    for (int i = 0; i < 64; i++) qr[i] = qp[i];
    int cmax = s/32 + 1;                       // blocked = c > (s*K)/S + SLACK
    for (int c = seg*16; c < seg*16 + 16; c++){
        float dot = 0.f;
        #pragma unroll
        for (int i = 0; i < 64; i++) dot = fmaf(qr[i], Ks[c][i], dot);
        Sc[r][c] = (c <= cmax) ? dot*0.125f : -1e30f;
    }
    __syncthreads();
    if (tid < 64){
        float m = -1e30f;
        for (int c = 0; c < 64; c++) m = fmaxf(m, Sc[tid][c]);
        float l = 0.f;
        for (int c = 0; c < 64; c++){ float e = expf(Sc[tid][c] - m); Sc[tid][c] = e; l += e; }
        float inv = 1.f / l;
        for (int c = 0; c < 64; c++) Sc[tid][c] *= inv;
    }
    __syncthreads();
    float accv[16] = {};
    for (int c = 0; c < 64; c++){
        float p = Sc[r][c];
        #pragma unroll
        for (int i = 0; i < 16; i++) accv[i] = fmaf(p, Vs[c][seg*16 + i], accv[i]);
    }
    float* op = o + ((long)(b*2048 + s))*1024 + h*64 + seg*16;
    #pragma unroll
    for (int i = 0; i < 16; i++) op[i] = accv[i];
}

// ---------------------------------------------------------------------------------
extern "C" void kernel_launch(void* const* d_in, const int* in_sizes, int n_in,
                              void* d_out, int out_size, void* d_ws, size_t ws_size,
                              hipStream_t stream)
{
    const float* tok   = (const float*)d_in[0];
    const float* crepr = (const float*)d_in[1];
    const float* cw    = (const float*)d_in[2];
    const float* n1    = (const float*)d_in[3];
    const float* cqkv  = (const float*)d_in[4];
    const float* co    = (const float*)d_in[5];
    const float* n2    = (const float*)d_in[6];
    const float* cw1   = (const float*)d_in[7];
    const float* cw2   = (const float*)d_in[8];
    const float* cw3   = (const float*)d_in[9];
    const float* dinw  = (const float*)d_in[10];
    const float* dinb  = (const float*)d_in[11];
    const float* doutw = (const float*)d_in[12];
    const float* doutb = (const float*)d_in[13];
    const float* dnw   = (const float*)d_in[14];
    const float* dfnw  = (const float*)d_in[15];
    const float* dw1   = (const float*)d_in[16];
    const float* dw2   = (const float*)d_in[17];
    const float* dw3   = (const float*)d_in[18];
    float* out = (float*)d_out;               // fp32 output per reference dtype

    // Workspace layout. fp32 except g_d (bf16). Total ~118 MB.
    float* F    = (float*)d_ws;
    int*   sidx = (int*)d_ws;                 // 256 ints (padded to 1024 floats)
    float* x_c  = F + 1024;                   // 256x1024
    float* h_c  = x_c  + 262144;              // 256x1024
    float* qkv_c= h_c  + 262144;              // 256x3072
    float* o_c  = qkv_c+ 786432;              // 256x1024
    float* g_c  = o_c  + 262144;              // 256x2730
    float* proc = g_c  + 698880;              // 256x1024
    float* kkb  = proc + 262144;              // 256x1024
    float* vvb  = kkb  + 262144;              // 256x1024
    float* q_d  = vvb  + 262144;              // 8192x1024 (reused: t1, then x2)
    float* attno= q_d  + 8388608;             // 8192x1024 (reused: y1)
    bf16*  g_d  = (bf16*)(attno + 8388608);   // 8192x2730 bf16

    // ---- Cascade processor ----
    sort_chunks_k<<<4, 64, 0, stream>>>(cw, sidx);
    gather_k<<<256, 256, 0, stream>>>(crepr, sidx, x_c);

    for (int l = 0; l < 2; l++){
        rms_k<<<256, 256, 0, stream>>>(x_c, n1 + l*1024, h_c);
        gemm_k<float,float,float><<<dim3(48,4), 256, 0, stream>>>(
            h_c, cqkv + (long)l*3145728, nullptr, nullptr, qkv_c, 256, 3072, 1024);
        casc_attn_k<<<64, 64, 0, stream>>>(qkv_c, o_c);
        gemm_k<float,float,float><<<dim3(16,4), 256, 0, stream>>>(
            o_c, co + (long)l*1048576, nullptr, x_c, x_c, 256, 1024, 1024);
        rms_k<<<256, 256, 0, stream>>>(x_c, n2 + l*1024, h_c);
        gemm_gated_k<float><<<dim3(43,4), 256, 0, stream>>>(
            h_c, cw1 + (long)l*2795520, cw3 + (long)l*2795520, g_c, 256, 2730, 1024);
        gemm_k<float,float,float><<<dim3(16,4), 256, 0, stream>>>(
            g_c, cw2 + (long)l*2795520, nullptr, x_c, x_c, 256, 1024, 2730);
    }
    scatter_k<<<256, 256, 0, stream>>>(x_c, sidx, proc);

    // ---- Chunk decoder ----
    gemm_k<float,float,float><<<dim3(16,128), 256, 0, stream>>>(
        tok, dinw, dinb, (const float*)nullptr, q_d, 8192, 1024, 1024);
    gemm_k<float,float,float><<<dim3(16,4), 256, 0, stream>>>(
        proc, dinw + 1048576, dinb + 1024, (const float*)nullptr, kkb, 256, 1024, 1024);
    gemm_k<float,float,float><<<dim3(16,4), 256, 0, stream>>>(
        proc, dinw + 2097152, dinb + 2048, (const float*)nullptr, vvb, 256, 1024, 1024);
    dec_attn_k<<<dim3(32,16,4), 256, 0, stream>>>(q_d, kkb, vvb, attno);
    // t1 = attno @ doutw^T + doutb + tok   -> q_d
    gemm_k<float,float,float><<<dim3(16,128), 256, 0, stream>>>(
        attno, doutw, doutb, tok, q_d, 8192, 1024, 1024);
    // y1 = rms(t1)*dec_norm_w -> attno
    rms_k<<<8192, 256, 0, stream>>>(q_d, dnw, attno);
    // x2 = rms(y1)*dec_ffn_norm_w -> q_d (t1 no longer needed)
    rms_k<<<8192, 256, 0, stream>>>(attno, dfnw, q_d);
    // g = silu(x2@w1^T)*(x2@w3^T) -> g_d (bf16)
    gemm_gated_k<bf16><<<dim3(43,128), 256, 0, stream>>>(q_d, dw1, dw3, g_d, 8192, 2730, 1024);
    // y = y1 + g@w2^T  -> fp32 out
    gemm_k<bf16,float,float><<<dim3(16,128), 256, 0, stream>>>(
        g_d, dw2, nullptr, attno, out, 8192, 1024, 2730);
}

// Round 4
// 3783.900 us; speedup vs baseline: 1.9811x; 1.9811x over previous
//
#include <hip/hip_runtime.h>
#include <hip/hip_bf16.h>
#include <math.h>

typedef __hip_bfloat16 bf16;
typedef __bf16 bf16x8 __attribute__((ext_vector_type(8)));
typedef float f32x4 __attribute__((ext_vector_type(4)));
typedef unsigned short ushort_t;

// Problem constants: B=4, S=2048, H=1024, K=64, NH=16, d=64, L=2, FF=2730 (pad 2816), EPS=1e-6
// Inputs fp32, output fp32. Decoder big GEMMs in bf16 MFMA (m97 structure).

__device__ __forceinline__ float ldf(const float* p, long i){ return p[i]; }
__device__ __forceinline__ void  stf(float* p, long i, float v){ p[i] = v; }
__device__ __forceinline__ void  stf(bf16*  p, long i, float v){ p[i] = __float2bfloat16(v); }

#define AS1 __attribute__((address_space(1)))
#define AS3 __attribute__((address_space(3)))

__device__ __forceinline__ void gl2lds16(const void* g, void* l){
    __builtin_amdgcn_global_load_lds((const AS1 void*)g, (AS3 void*)l, 16, 0, 0);
}

// ---------------- fp32 -> bf16 conversion with optional zero-padding -------------
// dst is rows_out x cols_out; src is rows_in x cols_in; pad region = 0.
__global__ __launch_bounds__(256) void cvt_pad_k(const float* __restrict__ src,
                                                 bf16* __restrict__ dst,
                                                 int rows_in, int cols_in, int cols_out){
    int r = blockIdx.x;
    const float* s = src + (long)r*cols_in;
    bf16* d = dst + (long)r*cols_out;
    bool rowok = r < rows_in;
    for (int c = threadIdx.x; c < cols_out; c += 256){
        float v = (rowok && c < cols_in) ? s[c] : 0.f;
        d[c] = __float2bfloat16(v);
    }
}

// ---------------- MFMA GEMM: C(fp32) = A(bf16,MxKd) @ W(bf16,NxKd)^T (+bias)(+Res)
// M mult of 128, N mult of 128 (buffers padded), Kd mult of 32.
__global__ __launch_bounds__(256) void mfma_gemm_k(
    const bf16* __restrict__ A, const bf16* __restrict__ W,
    const float* __restrict__ bias, const float* __restrict__ Res,
    float* __restrict__ C, int N, int Kd)
{
    __shared__ __align__(16) ushort_t As[128*32];
    __shared__ __align__(16) ushort_t Bs[128*32];
    const int tid = threadIdx.x;
    const int lane = tid & 63, wave = tid >> 6;
    const int wm = wave >> 1, wn = wave & 1;
    const int kg = lane >> 4, ln = lane & 15;
    const long bm = (long)blockIdx.y * 128, bn = (long)blockIdx.x * 128;

    const int srow = tid >> 2;          // 0..63
    const int scol = (tid & 3) * 8;     // 0,8,16,24
    const ushort_t* Ag = (const ushort_t*)A + (bm + srow)*(long)Kd + scol;
    const ushort_t* Wg = (const ushort_t*)W + (bn + srow)*(long)Kd + scol;
    ushort_t* Asd = &As[tid*8];
    ushort_t* Bsd = &Bs[tid*8];

    f32x4 acc[4][4] = {};
    for (int k0 = 0; k0 < Kd; k0 += 32){
        gl2lds16(Ag,               Asd);
        gl2lds16(Ag + (long)64*Kd, Asd + 2048);
        gl2lds16(Wg,               Bsd);
        gl2lds16(Wg + (long)64*Kd, Bsd + 2048);
        Ag += 32; Wg += 32;
        __syncthreads();
        bf16x8 af[4], bfr[4];
        #pragma unroll
        for (int t = 0; t < 4; t++){
            af[t]  = *(const bf16x8*)&As[(wm*64 + t*16 + ln)*32 + kg*8];
            bfr[t] = *(const bf16x8*)&Bs[(wn*64 + t*16 + ln)*32 + kg*8];
        }
        #pragma unroll
        for (int i = 0; i < 4; i++)
            #pragma unroll
            for (int j = 0; j < 4; j++)
                acc[i][j] = __builtin_amdgcn_mfma_f32_16x16x32_bf16(af[i], bfr[j], acc[i][j], 0, 0, 0);
        __syncthreads();
    }
    #pragma unroll
    for (int i = 0; i < 4; i++){
        long gm0 = bm + wm*64 + i*16 + kg*4;
        #pragma unroll
        for (int j = 0; j < 4; j++){
            long gn = bn + wn*64 + j*16 + ln;
            float bv = bias ? bias[gn] : 0.f;
            #pragma unroll
            for (int r = 0; r < 4; r++){
                long gm = gm0 + r;
                float v = acc[i][j][r] + bv;
                if (Res) v += Res[gm*N + gn];
                C[gm*N + gn] = v;
            }
        }
    }
}

// ---------------- MFMA gated GEMM: C(bf16) = silu(A@W1^T) * (A@W3^T) -------------
__global__ __launch_bounds__(256) void mfma_gated_k(
    const bf16* __restrict__ A, const bf16* __restrict__ W1,
    const bf16* __restrict__ W3, bf16* __restrict__ C, int Kd, int Nstride)
{
    __shared__ __align__(16) ushort_t As[128*32];
    __shared__ __align__(16) ushort_t B1s[128*32];
    __shared__ __align__(16) ushort_t B3s[128*32];
    const int tid = threadIdx.x;
    const int lane = tid & 63, wave = tid >> 6;
    const int wm = wave >> 1, wn = wave & 1;
    const int kg = lane >> 4, ln = lane & 15;
    const long bm = (long)blockIdx.y * 128, bn = (long)blockIdx.x * 128;

    const int srow = tid >> 2;
    const int scol = (tid & 3) * 8;
    const ushort_t* Ag  = (const ushort_t*)A  + (bm + srow)*(long)Kd + scol;
    const ushort_t* W1g = (const ushort_t*)W1 + (bn + srow)*(long)Kd + scol;
    const ushort_t* W3g = (const ushort_t*)W3 + (bn + srow)*(long)Kd + scol;
    ushort_t* Asd  = &As[tid*8];
    ushort_t* B1sd = &B1s[tid*8];
    ushort_t* B3sd = &B3s[tid*8];

    f32x4 acc1[4][4] = {};
    f32x4 acc3[4][4] = {};
    for (int k0 = 0; k0 < Kd; k0 += 32){
        gl2lds16(Ag,                Asd);
        gl2lds16(Ag  + (long)64*Kd, Asd + 2048);
        gl2lds16(W1g,               B1sd);
        gl2lds16(W1g + (long)64*Kd, B1sd + 2048);
        gl2lds16(W3g,               B3sd);
        gl2lds16(W3g + (long)64*Kd, B3sd + 2048);
        Ag += 32; W1g += 32; W3g += 32;
        __syncthreads();
        bf16x8 af[4], b1[4], b3[4];
        #pragma unroll
        for (int t = 0; t < 4; t++){
            af[t] = *(const bf16x8*)&As [(wm*64 + t*16 + ln)*32 + kg*8];
            b1[t] = *(const bf16x8*)&B1s[(wn*64 + t*16 + ln)*32 + kg*8];
            b3[t] = *(const bf16x8*)&B3s[(wn*64 + t*16 + ln)*32 + kg*8];
        }
        #pragma unroll
        for (int i = 0; i < 4; i++)
            #pragma unroll
            for (int j = 0; j < 4; j++){
                acc1[i][j] = __builtin_amdgcn_mfma_f32_16x16x32_bf16(af[i], b1[j], acc1[i][j], 0, 0, 0);
                acc3[i][j] = __builtin_amdgcn_mfma_f32_16x16x32_bf16(af[i], b3[j], acc3[i][j], 0, 0, 0);
            }
        __syncthreads();
    }
    #pragma unroll
    for (int i = 0; i < 4; i++){
        long gm0 = bm + wm*64 + i*16 + kg*4;
        #pragma unroll
        for (int j = 0; j < 4; j++){
            long gn = bn + wn*64 + j*16 + ln;
            #pragma unroll
            for (int r = 0; r < 4; r++){
                float x1 = acc1[i][j][r];
                float g  = x1 / (1.0f + expf(-x1));
                C[(gm0 + r)*Nstride + gn] = __float2bfloat16(g * acc3[i][j][r]);
            }
        }
    }
}

// ---------------- stable descending argsort of chunk_weights (K=64) -------------
__global__ void sort_chunks_k(const float* __restrict__ w, int* __restrict__ sidx){
    int b = blockIdx.x, t = threadIdx.x;
    __shared__ float ws_[64];
    ws_[t] = w[b*64 + t];
    __syncthreads();
    float mine = ws_[t];
    int rank = 0;
    for (int j = 0; j < 64; j++){
        float wj = ws_[j];
        rank += (wj > mine) || (wj == mine && j < t);
    }
    sidx[b*64 + rank] = t;
}

__global__ void gather_k(const float* __restrict__ src, const int* __restrict__ sidx,
                         float* __restrict__ dst){
    int row = blockIdx.x; int b = row >> 6, r = row & 63;
    int sr = sidx[b*64 + r];
    const float* s = src + ((long)(b*64 + sr))*1024;
    float* d = dst + (long)row*1024;
    for (int i = threadIdx.x; i < 1024; i += 256) d[i] = s[i];
}

__global__ void scatter_k(const float* __restrict__ x, const int* __restrict__ sidx,
                          float* __restrict__ proc){
    int row = blockIdx.x; int b = row >> 6, r = row & 63;
    int dr = sidx[b*64 + r];
    const float* s = x + (long)row*1024;
    float* d = proc + ((long)(b*64 + dr))*1024;
    for (int i = threadIdx.x; i < 1024; i += 256) d[i] = s[i];
}

// ---------------- RMSNorm (row length fixed 1024), templated output dtype --------
template<typename TO>
__global__ __launch_bounds__(256) void rms_k(const float* __restrict__ x,
                                             const float* __restrict__ w,
                                             TO* __restrict__ o){
    long row = blockIdx.x;
    const float* xr = x + row*1024;
    float v[4]; float ss = 0.f;
    #pragma unroll
    for (int j = 0; j < 4; j++){ v[j] = xr[threadIdx.x + j*256]; ss += v[j]*v[j]; }
    #pragma unroll
    for (int off = 32; off; off >>= 1) ss += __shfl_down(ss, off, 64);
    __shared__ float red[4];
    __shared__ float scale_s;
    int wave = threadIdx.x >> 6, lane = threadIdx.x & 63;
    if (lane == 0) red[wave] = ss;
    __syncthreads();
    if (threadIdx.x == 0){
        float t = red[0] + red[1] + red[2] + red[3];
        scale_s = rsqrtf(t * (1.0f/1024.f) + 1e-6f);
    }
    __syncthreads();
    float sc = scale_s;
    #pragma unroll
    for (int j = 0; j < 4; j++){
        int i = threadIdx.x + j*256;
        stf(o, row*1024 + i, v[j] * sc * w[i]);
    }
}

// ---------------- fp32 tiled GEMM (cascade, small M) ------------------------------
template<typename TC>
__global__ __launch_bounds__(256) void gemm_k(
    const float* __restrict__ A, const float* __restrict__ W,
    const float* __restrict__ bias, const float* __restrict__ Res,
    TC* __restrict__ C, int M, int N, int Kd)
{
    __shared__ float As[16][65];
    __shared__ float Ws[16][65];
    const int bm = blockIdx.y*64, bn = blockIdx.x*64;
    const int tid = threadIdx.x;
    const int tx = tid & 15, ty = tid >> 4;
    float acc[4][4] = {};
    for (int k0 = 0; k0 < Kd; k0 += 16){
        for (int e = tid; e < 1024; e += 256){
            int m = e >> 4, kk = e & 15;
            int gk = k0 + kk;
            int gm = bm + m;
            int gn = bn + m;
            As[kk][m] = (gm < M && gk < Kd) ? A[(long)gm*Kd + gk] : 0.f;
            Ws[kk][m] = (gn < N && gk < Kd) ? W[(long)gn*Kd + gk] : 0.f;
        }
        __syncthreads();
        #pragma unroll
        for (int kk = 0; kk < 16; kk++){
            float a[4], b[4];
            #pragma unroll
            for (int i = 0; i < 4; i++) a[i] = As[kk][ty*4+i];
            #pragma unroll
            for (int j = 0; j < 4; j++) b[j] = Ws[kk][tx*4+j];
            #pragma unroll
            for (int i = 0; i < 4; i++)
                #pragma unroll
                for (int j = 0; j < 4; j++)
                    acc[i][j] = fmaf(a[i], b[j], acc[i][j]);
        }
        __syncthreads();
    }
    #pragma unroll
    for (int i = 0; i < 4; i++){
        int m = bm + ty*4 + i;
        if (m >= M) continue;
        #pragma unroll
        for (int j = 0; j < 4; j++){
            int n = bn + tx*4 + j;
            if (n >= N) continue;
            float v = acc[i][j];
            if (bias) v += bias[n];
            if (Res)  v += ldf(Res, (long)m*N + n);
            stf(C, (long)m*N + n, v);
        }
    }
}

// ---------------- fp32 gated GEMM (cascade) ---------------------------------------
__global__ __launch_bounds__(256) void gemm_gated_f32_k(
    const float* __restrict__ A, const float* __restrict__ W1,
    const float* __restrict__ W3, float* __restrict__ C,
    int M, int N, int Kd)
{
    __shared__ float As [16][65];
    __shared__ float W1s[16][65];
    __shared__ float W3s[16][65];
    const int bm = blockIdx.y*64, bn = blockIdx.x*64;
    const int tid = threadIdx.x;
    const int tx = tid & 15, ty = tid >> 4;
    float acc1[4][4] = {};
    float acc3[4][4] = {};
    for (int k0 = 0; k0 < Kd; k0 += 16){
        for (int e = tid; e < 1024; e += 256){
            int m = e >> 4, kk = e & 15;
            int gk = k0 + kk;
            int gm = bm + m;
            int gn = bn + m;
            As [kk][m] = (gm < M && gk < Kd) ? A[(long)gm*Kd + gk] : 0.f;
            W1s[kk][m] = (gn < N && gk < Kd) ? W1[(long)gn*Kd + gk] : 0.f;
            W3s[kk][m] = (gn < N && gk < Kd) ? W3[(long)gn*Kd + gk] : 0.f;
        }
        __syncthreads();
        #pragma unroll
        for (int kk = 0; kk < 16; kk++){
            float a[4], b1[4], b3[4];
            #pragma unroll
            for (int i = 0; i < 4; i++) a[i]  = As[kk][ty*4+i];
            #pragma unroll
            for (int j = 0; j < 4; j++){ b1[j] = W1s[kk][tx*4+j]; b3[j] = W3s[kk][tx*4+j]; }
            #pragma unroll
            for (int i = 0; i < 4; i++)
                #pragma unroll
                for (int j = 0; j < 4; j++){
                    acc1[i][j] = fmaf(a[i], b1[j], acc1[i][j]);
                    acc3[i][j] = fmaf(a[i], b3[j], acc3[i][j]);
                }
        }
        __syncthreads();
    }
    #pragma unroll
    for (int i = 0; i < 4; i++){
        int m = bm + ty*4 + i;
        if (m >= M) continue;
        #pragma unroll
        for (int j = 0; j < 4; j++){
            int n = bn + tx*4 + j;
            if (n >= N) continue;
            float x1 = acc1[i][j];
            float g  = x1 / (1.0f + expf(-x1));
            C[(long)m*N + n] = g * acc3[i][j];
        }
    }
}

// ---------------- Cascade causal self-attention (K=64, d=64, per (b,h)) ----------
__global__ __launch_bounds__(64) void casc_attn_k(const float* __restrict__ qkv,
                                                  float* __restrict__ o){
    int b = blockIdx.x >> 4, h = blockIdx.x & 15;
    __shared__ float Ks[64][64], Vs[64][64], Sc[64][64];
    int t = threadIdx.x;
    const float* base = qkv + ((long)(b*64 + t))*3072 + h*64;
    float qr[64];
    #pragma unroll
    for (int i = 0; i < 64; i++){
        qr[i]    = base[i];
        Ks[t][i] = base[1024 + i];
        Vs[t][i] = base[2048 + i];
    }
    __syncthreads();
    float m = -1e30f;
    for (int j = 0; j <= t; j++){
        float dot = 0.f;
        #pragma unroll
        for (int i = 0; i < 64; i++) dot = fmaf(qr[i], Ks[j][i], dot);
        dot *= 0.125f;
        Sc[t][j] = dot;
        m = fmaxf(m, dot);
    }
    float l = 0.f;
    for (int j = 0; j <= t; j++){ float e = expf(Sc[t][j] - m); Sc[t][j] = e; l += e; }
    float inv = 1.f / l;
    float* op = o + ((long)(b*64 + t))*1024 + h*64;
    for (int i = 0; i < 64; i++){
        float acc = 0.f;
        for (int j = 0; j <= t; j++) acc = fmaf(Sc[t][j], Vs[j][i], acc);
        op[i] = acc * inv;
    }
}

// ---------------- Decoder cross-attention -> bf16 output -------------------------
__global__ __launch_bounds__(256) void dec_attn_k(const float* __restrict__ q,
    const float* __restrict__ kk, const float* __restrict__ vv, bf16* __restrict__ o){
    int s0 = blockIdx.x*64, h = blockIdx.y, b = blockIdx.z;
    __shared__ float Ks[64][64], Vs[64][64], Sc[64][65];
    int tid = threadIdx.x;
    for (int e = tid; e < 4096; e += 256){
        int c = e >> 6, i = e & 63;
        Ks[c][i] = kk[((long)(b*64 + c))*1024 + h*64 + i];
        Vs[c][i] = vv[((long)(b*64 + c))*1024 + h*64 + i];
    }
    __syncthreads();
    int r = tid >> 2, seg = tid & 3;
    int s = s0 + r;
    float qr[64];
    const float* qp = q + ((long)(b*2048 + s))*1024 + h*64;
    #pragma unroll
    for (int i = 0; i < 64; i++) qr[i] = qp[i];
    int cmax = s/32 + 1;
    for (int c = seg*16; c < seg*16 + 16; c++){
        float dot = 0.f;
        #pragma unroll
        for (int i = 0; i < 64; i++) dot = fmaf(qr[i], Ks[c][i], dot);
        Sc[r][c] = (c <= cmax) ? dot*0.125f : -1e30f;
    }
    __syncthreads();
    if (tid < 64){
        float m = -1e30f;
        for (int c = 0; c < 64; c++) m = fmaxf(m, Sc[tid][c]);
        float l = 0.f;
        for (int c = 0; c < 64; c++){ float e = expf(Sc[tid][c] - m); Sc[tid][c] = e; l += e; }
        float inv = 1.f / l;
        for (int c = 0; c < 64; c++) Sc[tid][c] *= inv;
    }
    __syncthreads();
    float accv[16] = {};
    for (int c = 0; c < 64; c++){
        float p = Sc[r][c];
        #pragma unroll
        for (int i = 0; i < 16; i++) accv[i] = fmaf(p, Vs[c][seg*16 + i], accv[i]);
    }
    bf16* op = o + ((long)(b*2048 + s))*1024 + h*64 + seg*16;
    #pragma unroll
    for (int i = 0; i < 16; i++) op[i] = __float2bfloat16(accv[i]);
}

// ---------------------------------------------------------------------------------
extern "C" void kernel_launch(void* const* d_in, const int* in_sizes, int n_in,
                              void* d_out, int out_size, void* d_ws, size_t ws_size,
                              hipStream_t stream)
{
    const float* tok   = (const float*)d_in[0];
    const float* crepr = (const float*)d_in[1];
    const float* cw    = (const float*)d_in[2];
    const float* n1    = (const float*)d_in[3];
    const float* cqkv  = (const float*)d_in[4];
    const float* co    = (const float*)d_in[5];
    const float* n2    = (const float*)d_in[6];
    const float* cw1   = (const float*)d_in[7];
    const float* cw2   = (const float*)d_in[8];
    const float* cw3   = (const float*)d_in[9];
    const float* dinw  = (const float*)d_in[10];
    const float* dinb  = (const float*)d_in[11];
    const float* doutw = (const float*)d_in[12];
    const float* doutb = (const float*)d_in[13];
    const float* dnw   = (const float*)d_in[14];
    const float* dfnw  = (const float*)d_in[15];
    const float* dw1   = (const float*)d_in[16];
    const float* dw2   = (const float*)d_in[17];
    const float* dw3   = (const float*)d_in[18];
    float* out = (float*)d_out;

    // Workspace layout (float units). Total ~180 MB.
    float* F = (float*)d_ws;
    long off = 0;
    int*   sidx  = (int*)d_ws;        off += 1024;
    float* x_c   = F + off;           off += 262144;    // 256x1024
    float* h_c   = F + off;           off += 262144;
    float* qkv_c = F + off;           off += 786432;    // 256x3072
    float* o_c   = F + off;           off += 262144;
    float* g_c   = F + off;           off += 698880;    // 256x2730
    float* proc  = F + off;           off += 262144;
    float* kkb   = F + off;           off += 262144;
    float* vvb   = F + off;           off += 262144;
    float* q_d   = F + off;           off += 8388608;   // 8192x1024 fp32 (q)
    float* y1    = F + off;           off += 8388608;   // 8192x1024 fp32
    bf16*  tok_bf= (bf16*)(F + off);  off += 4194304;   // 8192x1024 bf16 (later x2_bf)
    bf16*  att_bf= (bf16*)(F + off);  off += 4194304;   // 8192x1024 bf16
    bf16*  wq_bf = (bf16*)(F + off);  off += 524288;    // 1024x1024 bf16
    bf16*  wo_bf = (bf16*)(F + off);  off += 524288;
    bf16*  w1_bf = (bf16*)(F + off);  off += 1441792;   // 2816x1024 bf16
    bf16*  w3_bf = (bf16*)(F + off);  off += 1441792;
    bf16*  w2_bf = (bf16*)(F + off);  off += 1441792;   // 1024x2816 bf16
    float* t1    = F + off;                             // 8192x1024 fp32, region reused:
    bf16*  g_d   = (bf16*)(F + off);  off += 11534336;  // 8192x2816 bf16 (overwrites t1 after rms)
    bf16*  x2_bf = tok_bf;                              // reuse (tok_bf dead after q-proj)

    // ---- weight/activation bf16 conversions (independent of everything else) ----
    cvt_pad_k<<<8192, 256, 0, stream>>>(tok,   tok_bf, 8192, 1024, 1024);
    cvt_pad_k<<<1024, 256, 0, stream>>>(dinw,  wq_bf,  1024, 1024, 1024);
    cvt_pad_k<<<1024, 256, 0, stream>>>(doutw, wo_bf,  1024, 1024, 1024);
    cvt_pad_k<<<2816, 256, 0, stream>>>(dw1,   w1_bf,  2730, 1024, 1024);
    cvt_pad_k<<<2816, 256, 0, stream>>>(dw3,   w3_bf,  2730, 1024, 1024);
    cvt_pad_k<<<1024, 256, 0, stream>>>(dw2,   w2_bf,  1024, 2730, 2816);

    // ---- Cascade processor (fp32, small) ----
    sort_chunks_k<<<4, 64, 0, stream>>>(cw, sidx);
    gather_k<<<256, 256, 0, stream>>>(crepr, sidx, x_c);
    for (int l = 0; l < 2; l++){
        rms_k<float><<<256, 256, 0, stream>>>(x_c, n1 + l*1024, h_c);
        gemm_k<float><<<dim3(48,4), 256, 0, stream>>>(
            h_c, cqkv + (long)l*3145728, nullptr, nullptr, qkv_c, 256, 3072, 1024);
        casc_attn_k<<<64, 64, 0, stream>>>(qkv_c, o_c);
        gemm_k<float><<<dim3(16,4), 256, 0, stream>>>(
            o_c, co + (long)l*1048576, nullptr, x_c, x_c, 256, 1024, 1024);
        rms_k<float><<<256, 256, 0, stream>>>(x_c, n2 + l*1024, h_c);
        gemm_gated_f32_k<<<dim3(43,4), 256, 0, stream>>>(
            h_c, cw1 + (long)l*2795520, cw3 + (long)l*2795520, g_c, 256, 2730, 1024);
        gemm_k<float><<<dim3(16,4), 256, 0, stream>>>(
            g_c, cw2 + (long)l*2795520, nullptr, x_c, x_c, 256, 1024, 2730);
    }
    scatter_k<<<256, 256, 0, stream>>>(x_c, sidx, proc);

    // ---- Chunk decoder ----
    // q = tok @ wq^T + bq   (MFMA)
    mfma_gemm_k<<<dim3(8,64), 256, 0, stream>>>(tok_bf, wq_bf, dinb, nullptr, q_d, 1024, 1024);
    // k,v projections of processed chunks (tiny, fp32)
    gemm_k<float><<<dim3(16,4), 256, 0, stream>>>(
        proc, dinw + 1048576, dinb + 1024, nullptr, kkb, 256, 1024, 1024);
    gemm_k<float><<<dim3(16,4), 256, 0, stream>>>(
        proc, dinw + 2097152, dinb + 2048, nullptr, vvb, 256, 1024, 1024);
    dec_attn_k<<<dim3(32,16,4), 256, 0, stream>>>(q_d, kkb, vvb, att_bf);
    // t1 = attn @ doutw^T + doutb + tok   (MFMA, fp32 out into g_d region)
    mfma_gemm_k<<<dim3(8,64), 256, 0, stream>>>(att_bf, wo_bf, doutb, tok, t1, 1024, 1024);
    // y1 = rms(t1)*dec_norm_w (fp32); x2 = rms(y1)*dec_ffn_norm_w (bf16)
    rms_k<float><<<8192, 256, 0, stream>>>(t1, dnw, y1);
    rms_k<bf16> <<<8192, 256, 0, stream>>>(y1, dfnw, x2_bf);
    // g = silu(x2@w1^T)*(x2@w3^T) -> g_d (bf16, N padded to 2816; pad cols auto-zero)
    mfma_gated_k<<<dim3(22,64), 256, 0, stream>>>(x2_bf, w1_bf, w3_bf, g_d, 1024, 2816);
    // y = y1 + g@w2^T (MFMA, Kd=2816 incl. zero pad) -> fp32 out
    mfma_gemm_k<<<dim3(8,64), 256, 0, stream>>>(g_d, w2_bf, nullptr, y1, out, 1024, 2816);
}

// Round 5
// 1529.809 us; speedup vs baseline: 4.9002x; 2.4734x over previous
//
#include <hip/hip_runtime.h>
#include <hip/hip_bf16.h>
#include <math.h>

typedef __hip_bfloat16 bf16;
typedef __bf16 bf16x8 __attribute__((ext_vector_type(8)));
typedef float f32x4 __attribute__((ext_vector_type(4)));
typedef unsigned short ushort_t;

// Problem constants: B=4, S=2048, H=1024, K=64, NH=16, d=64, L=2, FF=2730 (pad 2816), EPS=1e-6
// Inputs fp32, output fp32. Decoder big GEMMs: bf16 MFMA (m97 structure).
// Small-M (M=256) GEMMs: fp32 split-K (Kc=128) + reduce — fixes latency starvation
// seen in round 4 (622us @ 2.6% VALUBusy, 3% occupancy, 1 block/CU lockstep barrier).

__device__ __forceinline__ float ldf(const float* p, long i){ return p[i]; }
__device__ __forceinline__ void  stf(float* p, long i, float v){ p[i] = v; }
__device__ __forceinline__ void  stf(bf16*  p, long i, float v){ p[i] = __float2bfloat16(v); }

#define AS1 __attribute__((address_space(1)))
#define AS3 __attribute__((address_space(3)))

__device__ __forceinline__ void gl2lds16(const void* g, void* l){
    __builtin_amdgcn_global_load_lds((const AS1 void*)g, (AS3 void*)l, 16, 0, 0);
}

// ---------------- fp32 -> bf16 conversion with optional zero-padding -------------
__global__ __launch_bounds__(256) void cvt_pad_k(const float* __restrict__ src,
                                                 bf16* __restrict__ dst,
                                                 int rows_in, int cols_in, int cols_out){
    int r = blockIdx.x;
    const float* s = src + (long)r*cols_in;
    bf16* d = dst + (long)r*cols_out;
    bool rowok = r < rows_in;
    for (int c = threadIdx.x; c < cols_out; c += 256){
        float v = (rowok && c < cols_in) ? s[c] : 0.f;
        d[c] = __float2bfloat16(v);
    }
}

// ---------------- MFMA GEMM: C(fp32) = A(bf16,MxKd) @ W(bf16,NxKd)^T (+bias)(+Res)
__global__ __launch_bounds__(256) void mfma_gemm_k(
    const bf16* __restrict__ A, const bf16* __restrict__ W,
    const float* __restrict__ bias, const float* __restrict__ Res,
    float* __restrict__ C, int N, int Kd)
{
    __shared__ __align__(16) ushort_t As[128*32];
    __shared__ __align__(16) ushort_t Bs[128*32];
    const int tid = threadIdx.x;
    const int lane = tid & 63, wave = tid >> 6;
    const int wm = wave >> 1, wn = wave & 1;
    const int kg = lane >> 4, ln = lane & 15;
    const long bm = (long)blockIdx.y * 128, bn = (long)blockIdx.x * 128;

    const int srow = tid >> 2;
    const int scol = (tid & 3) * 8;
    const ushort_t* Ag = (const ushort_t*)A + (bm + srow)*(long)Kd + scol;
    const ushort_t* Wg = (const ushort_t*)W + (bn + srow)*(long)Kd + scol;
    ushort_t* Asd = &As[tid*8];
    ushort_t* Bsd = &Bs[tid*8];

    f32x4 acc[4][4] = {};
    for (int k0 = 0; k0 < Kd; k0 += 32){
        gl2lds16(Ag,               Asd);
        gl2lds16(Ag + (long)64*Kd, Asd + 2048);
        gl2lds16(Wg,               Bsd);
        gl2lds16(Wg + (long)64*Kd, Bsd + 2048);
        Ag += 32; Wg += 32;
        __syncthreads();
        bf16x8 af[4], bfr[4];
        #pragma unroll
        for (int t = 0; t < 4; t++){
            af[t]  = *(const bf16x8*)&As[(wm*64 + t*16 + ln)*32 + kg*8];
            bfr[t] = *(const bf16x8*)&Bs[(wn*64 + t*16 + ln)*32 + kg*8];
        }
        #pragma unroll
        for (int i = 0; i < 4; i++)
            #pragma unroll
            for (int j = 0; j < 4; j++)
                acc[i][j] = __builtin_amdgcn_mfma_f32_16x16x32_bf16(af[i], bfr[j], acc[i][j], 0, 0, 0);
        __syncthreads();
    }
    #pragma unroll
    for (int i = 0; i < 4; i++){
        long gm0 = bm + wm*64 + i*16 + kg*4;
        #pragma unroll
        for (int j = 0; j < 4; j++){
            long gn = bn + wn*64 + j*16 + ln;
            float bv = bias ? bias[gn] : 0.f;
            #pragma unroll
            for (int r = 0; r < 4; r++){
                long gm = gm0 + r;
                float v = acc[i][j][r] + bv;
                if (Res) v += Res[gm*N + gn];
                C[gm*N + gn] = v;
            }
        }
    }
}

// ---------------- MFMA gated GEMM: C(bf16) = silu(A@W1^T) * (A@W3^T) -------------
__global__ __launch_bounds__(256) void mfma_gated_k(
    const bf16* __restrict__ A, const bf16* __restrict__ W1,
    const bf16* __restrict__ W3, bf16* __restrict__ C, int Kd, int Nstride)
{
    __shared__ __align__(16) ushort_t As[128*32];
    __shared__ __align__(16) ushort_t B1s[128*32];
    __shared__ __align__(16) ushort_t B3s[128*32];
    const int tid = threadIdx.x;
    const int lane = tid & 63, wave = tid >> 6;
    const int wm = wave >> 1, wn = wave & 1;
    const int kg = lane >> 4, ln = lane & 15;
    const long bm = (long)blockIdx.y * 128, bn = (long)blockIdx.x * 128;

    const int srow = tid >> 2;
    const int scol = (tid & 3) * 8;
    const ushort_t* Ag  = (const ushort_t*)A  + (bm + srow)*(long)Kd + scol;
    const ushort_t* W1g = (const ushort_t*)W1 + (bn + srow)*(long)Kd + scol;
    const ushort_t* W3g = (const ushort_t*)W3 + (bn + srow)*(long)Kd + scol;
    ushort_t* Asd  = &As[tid*8];
    ushort_t* B1sd = &B1s[tid*8];
    ushort_t* B3sd = &B3s[tid*8];

    f32x4 acc1[4][4] = {};
    f32x4 acc3[4][4] = {};
    for (int k0 = 0; k0 < Kd; k0 += 32){
        gl2lds16(Ag,                Asd);
        gl2lds16(Ag  + (long)64*Kd, Asd + 2048);
        gl2lds16(W1g,               B1sd);
        gl2lds16(W1g + (long)64*Kd, B1sd + 2048);
        gl2lds16(W3g,               B3sd);
        gl2lds16(W3g + (long)64*Kd, B3sd + 2048);
        Ag += 32; W1g += 32; W3g += 32;
        __syncthreads();
        bf16x8 af[4], b1[4], b3[4];
        #pragma unroll
        for (int t = 0; t < 4; t++){
            af[t] = *(const bf16x8*)&As [(wm*64 + t*16 + ln)*32 + kg*8];
            b1[t] = *(const bf16x8*)&B1s[(wn*64 + t*16 + ln)*32 + kg*8];
            b3[t] = *(const bf16x8*)&B3s[(wn*64 + t*16 + ln)*32 + kg*8];
        }
        #pragma unroll
        for (int i = 0; i < 4; i++)
            #pragma unroll
            for (int j = 0; j < 4; j++){
                acc1[i][j] = __builtin_amdgcn_mfma_f32_16x16x32_bf16(af[i], b1[j], acc1[i][j], 0, 0, 0);
                acc3[i][j] = __builtin_amdgcn_mfma_f32_16x16x32_bf16(af[i], b3[j], acc3[i][j], 0, 0, 0);
            }
        __syncthreads();
    }
    #pragma unroll
    for (int i = 0; i < 4; i++){
        long gm0 = bm + wm*64 + i*16 + kg*4;
        #pragma unroll
        for (int j = 0; j < 4; j++){
            long gn = bn + wn*64 + j*16 + ln;
            #pragma unroll
            for (int r = 0; r < 4; r++){
                float x1 = acc1[i][j][r];
                float g  = x1 / (1.0f + expf(-x1));
                C[(gm0 + r)*Nstride + gn] = __float2bfloat16(g * acc3[i][j][r]);
            }
        }
    }
}

// ---------------- fp32 split-K GEMM: P[kz] = A(MxKd) @ W(NxKd)^T chunk -----------
// grid (N/64, M/64, KS), Kc per z-chunk. Partials, no bias/res.
__global__ __launch_bounds__(256) void gemm_sk_k(
    const float* __restrict__ A, const float* __restrict__ W,
    float* __restrict__ P, int M, int N, int Kd, int Kc)
{
    __shared__ float As[16][65];
    __shared__ float Ws[16][65];
    const int bm = blockIdx.y*64, bn = blockIdx.x*64;
    const int kz = blockIdx.z;
    const int kbeg = kz*Kc, kend = min(kbeg + Kc, Kd);
    const int tid = threadIdx.x;
    const int tx = tid & 15, ty = tid >> 4;
    float acc[4][4] = {};
    for (int k0 = kbeg; k0 < kend; k0 += 16){
        for (int e = tid; e < 1024; e += 256){
            int m = e >> 4, kk = e & 15;
            int gk = k0 + kk;
            int gm = bm + m;
            int gn = bn + m;
            As[kk][m] = (gm < M && gk < kend) ? A[(long)gm*Kd + gk] : 0.f;
            Ws[kk][m] = (gn < N && gk < kend) ? W[(long)gn*Kd + gk] : 0.f;
        }
        __syncthreads();
        #pragma unroll
        for (int kk = 0; kk < 16; kk++){
            float a[4], b[4];
            #pragma unroll
            for (int i = 0; i < 4; i++) a[i] = As[kk][ty*4+i];
            #pragma unroll
            for (int j = 0; j < 4; j++) b[j] = Ws[kk][tx*4+j];
            #pragma unroll
            for (int i = 0; i < 4; i++)
                #pragma unroll
                for (int j = 0; j < 4; j++)
                    acc[i][j] = fmaf(a[i], b[j], acc[i][j]);
        }
        __syncthreads();
    }
    float* Pz = P + (long)kz*M*N;
    #pragma unroll
    for (int i = 0; i < 4; i++){
        int m = bm + ty*4 + i;
        if (m >= M) continue;
        #pragma unroll
        for (int j = 0; j < 4; j++){
            int n = bn + tx*4 + j;
            if (n >= N) continue;
            Pz[(long)m*N + n] = acc[i][j];
        }
    }
}

// ---------------- reduce: C = sum_ks P (+bias)(+Res) ------------------------------
__global__ __launch_bounds__(256) void reduce_plain_k(
    const float* __restrict__ P, int KS, const float* __restrict__ bias,
    const float* __restrict__ Res, float* __restrict__ C, long MN, int N)
{
    long i = (long)blockIdx.x*256 + threadIdx.x;
    if (i >= MN) return;
    float s = 0.f;
    for (int k = 0; k < KS; k++) s += P[(long)k*MN + i];
    if (bias) s += bias[i % N];
    if (Res)  s += Res[i];
    C[i] = s;
}

// ---------------- reduce gated: C = silu(sum P1) * (sum P3) -----------------------
__global__ __launch_bounds__(256) void reduce_gated_k(
    const float* __restrict__ P1, const float* __restrict__ P3, int KS,
    float* __restrict__ C, long MN)
{
    long i = (long)blockIdx.x*256 + threadIdx.x;
    if (i >= MN) return;
    float s1 = 0.f, s3 = 0.f;
    for (int k = 0; k < KS; k++){ s1 += P1[(long)k*MN + i]; s3 += P3[(long)k*MN + i]; }
    float g = s1 / (1.0f + expf(-s1));
    C[i] = g * s3;
}

// ---------------- stable descending argsort of chunk_weights (K=64) -------------
__global__ void sort_chunks_k(const float* __restrict__ w, int* __restrict__ sidx){
    int b = blockIdx.x, t = threadIdx.x;
    __shared__ float ws_[64];
    ws_[t] = w[b*64 + t];
    __syncthreads();
    float mine = ws_[t];
    int rank = 0;
    for (int j = 0; j < 64; j++){
        float wj = ws_[j];
        rank += (wj > mine) || (wj == mine && j < t);
    }
    sidx[b*64 + rank] = t;
}

__global__ void gather_k(const float* __restrict__ src, const int* __restrict__ sidx,
                         float* __restrict__ dst){
    int row = blockIdx.x; int b = row >> 6, r = row & 63;
    int sr = sidx[b*64 + r];
    const float* s = src + ((long)(b*64 + sr))*1024;
    float* d = dst + (long)row*1024;
    for (int i = threadIdx.x; i < 1024; i += 256) d[i] = s[i];
}

__global__ void scatter_k(const float* __restrict__ x, const int* __restrict__ sidx,
                          float* __restrict__ proc){
    int row = blockIdx.x; int b = row >> 6, r = row & 63;
    int dr = sidx[b*64 + r];
    const float* s = x + (long)row*1024;
    float* d = proc + ((long)(b*64 + dr))*1024;
    for (int i = threadIdx.x; i < 1024; i += 256) d[i] = s[i];
}

// ---------------- RMSNorm (row length fixed 1024) --------------------------------
template<typename TO>
__global__ __launch_bounds__(256) void rms_k(const float* __restrict__ x,
                                             const float* __restrict__ w,
                                             TO* __restrict__ o){
    long row = blockIdx.x;
    const float* xr = x + row*1024;
    float v[4]; float ss = 0.f;
    #pragma unroll
    for (int j = 0; j < 4; j++){ v[j] = xr[threadIdx.x + j*256]; ss += v[j]*v[j]; }
    #pragma unroll
    for (int off = 32; off; off >>= 1) ss += __shfl_down(ss, off, 64);
    __shared__ float red[4];
    __shared__ float scale_s;
    int wave = threadIdx.x >> 6, lane = threadIdx.x & 63;
    if (lane == 0) red[wave] = ss;
    __syncthreads();
    if (threadIdx.x == 0){
        float t = red[0] + red[1] + red[2] + red[3];
        scale_s = rsqrtf(t * (1.0f/1024.f) + 1e-6f);
    }
    __syncthreads();
    float sc = scale_s;
    #pragma unroll
    for (int j = 0; j < 4; j++){
        int i = threadIdx.x + j*256;
        stf(o, row*1024 + i, v[j] * sc * w[i]);
    }
}

// ---------------- Cascade causal self-attention (K=64, d=64, per (b,h)) ----------
__global__ __launch_bounds__(64) void casc_attn_k(const float* __restrict__ qkv,
                                                  float* __restrict__ o){
    int b = blockIdx.x >> 4, h = blockIdx.x & 15;
    __shared__ float Ks[64][64], Vs[64][64], Sc[64][64];
    int t = threadIdx.x;
    const float* base = qkv + ((long)(b*64 + t))*3072 + h*64;
    float qr[64];
    #pragma unroll
    for (int i = 0; i < 64; i++){
        qr[i]    = base[i];
        Ks[t][i] = base[1024 + i];
        Vs[t][i] = base[2048 + i];
    }
    __syncthreads();
    float m = -1e30f;
    for (int j = 0; j <= t; j++){
        float dot = 0.f;
        #pragma unroll
        for (int i = 0; i < 64; i++) dot = fmaf(qr[i], Ks[j][i], dot);
        dot *= 0.125f;
        Sc[t][j] = dot;
        m = fmaxf(m, dot);
    }
    float l = 0.f;
    for (int j = 0; j <= t; j++){ float e = expf(Sc[t][j] - m); Sc[t][j] = e; l += e; }
    float inv = 1.f / l;
    float* op = o + ((long)(b*64 + t))*1024 + h*64;
    for (int i = 0; i < 64; i++){
        float acc = 0.f;
        for (int j = 0; j <= t; j++) acc = fmaf(Sc[t][j], Vs[j][i], acc);
        op[i] = acc * inv;
    }
}

// ---------------- Decoder cross-attention -> bf16 output -------------------------
__global__ __launch_bounds__(256) void dec_attn_k(const float* __restrict__ q,
    const float* __restrict__ kk, const float* __restrict__ vv, bf16* __restrict__ o){
    int s0 = blockIdx.x*64, h = blockIdx.y, b = blockIdx.z;
    __shared__ float Ks[64][64], Vs[64][64], Sc[64][65];
    int tid = threadIdx.x;
    for (int e = tid; e < 4096; e += 256){
        int c = e >> 6, i = e & 63;
        Ks[c][i] = kk[((long)(b*64 + c))*1024 + h*64 + i];
        Vs[c][i] = vv[((long)(b*64 + c))*1024 + h*64 + i];
    }
    __syncthreads();
    int r = tid >> 2, seg = tid & 3;
    int s = s0 + r;
    float qr[64];
    const float* qp = q + ((long)(b*2048 + s))*1024 + h*64;
    #pragma unroll
    for (int i = 0; i < 64; i++) qr[i] = qp[i];
    int cmax = s/32 + 1;
    for (int c = seg*16; c < seg*16 + 16; c++){
        float dot = 0.f;
        #pragma unroll
        for (int i = 0; i < 64; i++) dot = fmaf(qr[i], Ks[c][i], dot);
        Sc[r][c] = (c <= cmax) ? dot*0.125f : -1e30f;
    }
    __syncthreads();
    if (tid < 64){
        float m = -1e30f;
        for (int c = 0; c < 64; c++) m = fmaxf(m, Sc[tid][c]);
        float l = 0.f;
        for (int c = 0; c < 64; c++){ float e = expf(Sc[tid][c] - m); Sc[tid][c] = e; l += e; }
        float inv = 1.f / l;
        for (int c = 0; c < 64; c++) Sc[tid][c] *= inv;
    }
    __syncthreads();
    float accv[16] = {};
    for (int c = 0; c < 64; c++){
        float p = Sc[r][c];
        #pragma unroll
        for (int i = 0; i < 16; i++) accv[i] = fmaf(p, Vs[c][seg*16 + i], accv[i]);
    }
    bf16* op = o + ((long)(b*2048 + s))*1024 + h*64 + seg*16;
    #pragma unroll
    for (int i = 0; i < 16; i++) op[i] = __float2bfloat16(accv[i]);
}

// ---------------------------------------------------------------------------------
extern "C" void kernel_launch(void* const* d_in, const int* in_sizes, int n_in,
                              void* d_out, int out_size, void* d_ws, size_t ws_size,
                              hipStream_t stream)
{
    const float* tok   = (const float*)d_in[0];
    const float* crepr = (const float*)d_in[1];
    const float* cw    = (const float*)d_in[2];
    const float* n1    = (const float*)d_in[3];
    const float* cqkv  = (const float*)d_in[4];
    const float* co    = (const float*)d_in[5];
    const float* n2    = (const float*)d_in[6];
    const float* cw1   = (const float*)d_in[7];
    const float* cw2   = (const float*)d_in[8];
    const float* cw3   = (const float*)d_in[9];
    const float* dinw  = (const float*)d_in[10];
    const float* dinb  = (const float*)d_in[11];
    const float* doutw = (const float*)d_in[12];
    const float* doutb = (const float*)d_in[13];
    const float* dnw   = (const float*)d_in[14];
    const float* dfnw  = (const float*)d_in[15];
    const float* dw1   = (const float*)d_in[16];
    const float* dw2   = (const float*)d_in[17];
    const float* dw3   = (const float*)d_in[18];
    float* out = (float*)d_out;

    // Workspace layout (float units). Same total as round 4 (~180 MB).
    float* F = (float*)d_ws;
    long off = 0;
    int*   sidx  = (int*)d_ws;        off += 1024;
    float* x_c   = F + off;           off += 262144;    // 256x1024
    float* h_c   = F + off;           off += 262144;
    float* qkv_c = F + off;           off += 786432;    // 256x3072
    float* o_c   = F + off;           off += 262144;
    float* g_c   = F + off;           off += 698880;    // 256x2730
    float* proc  = F + off;           off += 262144;
    float* kkb   = F + off;           off += 262144;
    float* vvb   = F + off;           off += 262144;
    float* q_d   = F + off;           off += 8388608;   // 8192x1024 fp32
    float* y1    = F + off;           off += 8388608;   // 8192x1024 fp32
    bf16*  tok_bf= (bf16*)(F + off);  off += 4194304;   // 8192x1024 bf16
    bf16*  att_bf= (bf16*)(F + off);  off += 4194304;   // 8192x1024 bf16
    bf16*  wq_bf = (bf16*)(F + off);  off += 524288;    // 1024x1024 bf16
    bf16*  wo_bf = (bf16*)(F + off);  off += 524288;
    bf16*  w1_bf = (bf16*)(F + off);  off += 1441792;   // 2816x1024 bf16
    bf16*  w3_bf = (bf16*)(F + off);  off += 1441792;
    bf16*  w2_bf = (bf16*)(F + off);  off += 1441792;   // 1024x2816 bf16
    float* t1    = F + off;
    bf16*  g_d   = (bf16*)(F + off);  off += 11534336;  // 8192x2816 bf16 (t1 overlays)
    bf16*  x2_bf = tok_bf;                              // reuse after q-proj

    // Split-K partial pool: aliases q_d..y1 (16.78M floats, dead during cascade +
    // k/v projections, which all complete before q-proj writes q_d).
    float* P  = q_d;                  // up to ~11.2M floats used
    float* P3 = q_d + 5591040;        // second gated partial (8*256*2730)

    // ---- bf16 conversions (decoder weights/activations) ----
    cvt_pad_k<<<8192, 256, 0, stream>>>(tok,   tok_bf, 8192, 1024, 1024);
    cvt_pad_k<<<1024, 256, 0, stream>>>(dinw,  wq_bf,  1024, 1024, 1024);
    cvt_pad_k<<<1024, 256, 0, stream>>>(doutw, wo_bf,  1024, 1024, 1024);
    cvt_pad_k<<<2816, 256, 0, stream>>>(dw1,   w1_bf,  2730, 1024, 1024);
    cvt_pad_k<<<2816, 256, 0, stream>>>(dw3,   w3_bf,  2730, 1024, 1024);
    cvt_pad_k<<<1024, 256, 0, stream>>>(dw2,   w2_bf,  1024, 2730, 2816);

    // ---- Cascade processor (fp32 split-K) ----
    sort_chunks_k<<<4, 64, 0, stream>>>(cw, sidx);
    gather_k<<<256, 256, 0, stream>>>(crepr, sidx, x_c);
    for (int l = 0; l < 2; l++){
        rms_k<float><<<256, 256, 0, stream>>>(x_c, n1 + l*1024, h_c);
        // qkv: 256x3072 = h @ cqkv^T, K=1024, KS=8
        gemm_sk_k<<<dim3(48,4,8), 256, 0, stream>>>(
            h_c, cqkv + (long)l*3145728, P, 256, 3072, 1024, 128);
        reduce_plain_k<<<3072, 256, 0, stream>>>(P, 8, nullptr, nullptr, qkv_c, 786432, 3072);
        casc_attn_k<<<64, 64, 0, stream>>>(qkv_c, o_c);
        // o-proj: x += o @ co^T, K=1024, KS=8
        gemm_sk_k<<<dim3(16,4,8), 256, 0, stream>>>(
            o_c, co + (long)l*1048576, P, 256, 1024, 1024, 128);
        reduce_plain_k<<<1024, 256, 0, stream>>>(P, 8, nullptr, x_c, x_c, 262144, 1024);
        rms_k<float><<<256, 256, 0, stream>>>(x_c, n2 + l*1024, h_c);
        // gated FFN: P1 = h@w1^T, P3 = h@w3^T (N=2730, 43 n-tiles), KS=8
        gemm_sk_k<<<dim3(43,4,8), 256, 0, stream>>>(
            h_c, cw1 + (long)l*2795520, P,  256, 2730, 1024, 128);
        gemm_sk_k<<<dim3(43,4,8), 256, 0, stream>>>(
            h_c, cw3 + (long)l*2795520, P3, 256, 2730, 1024, 128);
        reduce_gated_k<<<2730, 256, 0, stream>>>(P, P3, 8, g_c, 698880);
        // w2: x += g @ cw2^T, K=2730, KS=22 (Kc=128)
        gemm_sk_k<<<dim3(16,4,22), 256, 0, stream>>>(
            g_c, cw2 + (long)l*2795520, P, 256, 1024, 2730, 128);
        reduce_plain_k<<<1024, 256, 0, stream>>>(P, 22, nullptr, x_c, x_c, 262144, 1024);
    }
    scatter_k<<<256, 256, 0, stream>>>(x_c, sidx, proc);

    // ---- Decoder k/v projections (fp32 split-K, before q-proj overwrites P region)
    gemm_sk_k<<<dim3(16,4,8), 256, 0, stream>>>(
        proc, dinw + 1048576, P, 256, 1024, 1024, 128);
    reduce_plain_k<<<1024, 256, 0, stream>>>(P, 8, dinb + 1024, nullptr, kkb, 262144, 1024);
    gemm_sk_k<<<dim3(16,4,8), 256, 0, stream>>>(
        proc, dinw + 2097152, P, 256, 1024, 1024, 128);
    reduce_plain_k<<<1024, 256, 0, stream>>>(P, 8, dinb + 2048, nullptr, vvb, 262144, 1024);

    // ---- Decoder big GEMMs (bf16 MFMA) ----
    // q = tok @ wq^T + bq
    mfma_gemm_k<<<dim3(8,64), 256, 0, stream>>>(tok_bf, wq_bf, dinb, nullptr, q_d, 1024, 1024);
    dec_attn_k<<<dim3(32,16,4), 256, 0, stream>>>(q_d, kkb, vvb, att_bf);
    // t1 = attn @ doutw^T + doutb + tok
    mfma_gemm_k<<<dim3(8,64), 256, 0, stream>>>(att_bf, wo_bf, doutb, tok, t1, 1024, 1024);
    // y1 = rms(t1)*dec_norm_w ; x2 = rms(y1)*dec_ffn_norm_w
    rms_k<float><<<8192, 256, 0, stream>>>(t1, dnw, y1);
    rms_k<bf16> <<<8192, 256, 0, stream>>>(y1, dfnw, x2_bf);
    // g = silu(x2@w1^T)*(x2@w3^T) -> g_d (bf16, N padded 2816)
    mfma_gated_k<<<dim3(22,64), 256, 0, stream>>>(x2_bf, w1_bf, w3_bf, g_d, 1024, 2816);
    // y = y1 + g@w2^T -> fp32 out
    mfma_gemm_k<<<dim3(8,64), 256, 0, stream>>>(g_d, w2_bf, nullptr, y1, out, 1024, 2816);
}